// Round 10
// baseline (283.963 us; speedup 1.0000x reference)
//
#include <hip/hip_runtime.h>
#include <hip/hip_fp16.h>

#define F_IN 128
#define HID  64
#define CAP  96      // max edges per dst node (degrees ~Poisson(16), max ~45)

typedef short s16x8 __attribute__((ext_vector_type(8)));   // 8 bf16 (4 VGPRs) MFMA operand
typedef float f32x4 __attribute__((ext_vector_type(4)));   // MFMA accumulator

// bf16 round-to-nearest-even, pure int ops (no __bf16 dependence)
__device__ inline unsigned short bf16rne(float f) {
    unsigned u = __float_as_uint(f);
    return (unsigned short)((u + 0x7FFFu + ((u >> 16) & 1u)) >> 16);
}
__device__ inline float bf16tof(unsigned short h) {
    return __uint_as_float(((unsigned)h) << 16);
}

// ---------------- W1 split: fp32 [128][64] -> two bf16 transposed copies [64][128] ----------------
__launch_bounds__(512)
__global__ void k_wsplit(const float* __restrict__ W1, unsigned short* __restrict__ W1hT,
                         unsigned short* __restrict__ W1lT) {
    int id = blockIdx.x * 512 + threadIdx.x;   // 0..8191 ; id = k*64 + c
    int k = id >> 6, c = id & 63;
    float f = W1[id];
    unsigned short h = bf16rne(f);
    unsigned short l = bf16rne(f - bf16tof(h));
    W1hT[c * F_IN + k] = h;
    W1lT[c * F_IN + k] = l;
}

// ---------------- CSR build: direct per-node atomic scatter (replaces coarse+fillc) ----------------
// counts pre-zeroed. Per edge: p = atomicAdd(&counts[d],1); csrc[d*CAP+p] = s.
// counts (400KB) is L2-resident; csrc row slots for one node share cache lines, and the
// 38MB csrc fits L3 -> HBM write traffic ~ same as the 2-pass scheme. Sums are
// order-invariant so arbitrary slot order is correct. 4 edges/thread, loads first (MLP),
// then atomics, then stores.
__launch_bounds__(256)
__global__ void k_scatter(const int* __restrict__ src, const int* __restrict__ dst,
                          int* __restrict__ counts, int* __restrict__ csrc, int E) {
    int base = blockIdx.x * 1024 + threadIdx.x;
    int d[4], s[4]; bool v[4]; int p[4];
#pragma unroll
    for (int k = 0; k < 4; ++k) {
        int e = base + k * 256;
        v[k] = (e < E);
        d[k] = v[k] ? dst[e] : 0;
        s[k] = v[k] ? src[e] : 0;
    }
#pragma unroll
    for (int k = 0; k < 4; ++k)
        if (v[k]) p[k] = atomicAdd(&counts[d[k]], 1);
#pragma unroll
    for (int k = 0; k < 4; ++k)
        if (v[k] && p[k] < CAP) csrc[(size_t)d[k] * CAP + p[k]] = s[k];
}

// ---------------- GEMM via MFMA: hn = fp16( (x @ W1) * dinv(row) ) ----------------
// (round-6 form: no LDS, no barriers; measured best of the three gemm engines)
__launch_bounds__(256)
__global__ void k_gemm(const float* __restrict__ x,
                       const unsigned short* __restrict__ W1hT,
                       const unsigned short* __restrict__ W1lT,
                       const int* __restrict__ counts, __half* __restrict__ hn, int N) {
    int t = threadIdx.x;
    int lane = t & 63;
    int wid = t >> 6;
    int r0w = blockIdx.x * 64 + wid * 16;     // wave's 16-row base
    int arow = r0w + (lane & 15);
    int ar = (arow < N) ? arow : (N - 1);     // clamp; out-of-range rows never stored
    int kq = lane >> 4;                        // k-quarter 0..3

    const float* xr = x + (size_t)ar * F_IN + kq * 8;
    int coff = (lane & 15) * F_IN + kq * 8;    // elem offset in [col][k] bf16 layout

    f32x4 acc[4];
#pragma unroll
    for (int nt = 0; nt < 4; ++nt) acc[nt] = (f32x4){0.f, 0.f, 0.f, 0.f};

#pragma unroll
    for (int kt = 0; kt < 4; ++kt) {
        float4 xa = *(const float4*)(xr + kt * 32);
        float4 xb = *(const float4*)(xr + kt * 32 + 4);
        float xf[8] = {xa.x, xa.y, xa.z, xa.w, xb.x, xb.y, xb.z, xb.w};
        s16x8 ah, al;
#pragma unroll
        for (int j = 0; j < 8; ++j) {
            unsigned short h = bf16rne(xf[j]);
            ah[j] = (short)h;
            al[j] = (short)bf16rne(xf[j] - bf16tof(h));
        }
        int kb = coff + kt * 32;
#pragma unroll
        for (int nt = 0; nt < 4; ++nt) {
            s16x8 bh = *(const s16x8*)(W1hT + nt * 16 * F_IN + kb);
            s16x8 bl = *(const s16x8*)(W1lT + nt * 16 * F_IN + kb);
            acc[nt] = __builtin_amdgcn_mfma_f32_16x16x32_bf16(ah, bh, acc[nt], 0, 0, 0);
            acc[nt] = __builtin_amdgcn_mfma_f32_16x16x32_bf16(al, bh, acc[nt], 0, 0, 0);
            acc[nt] = __builtin_amdgcn_mfma_f32_16x16x32_bf16(ah, bl, acc[nt], 0, 0, 0);
            acc[nt] = __builtin_amdgcn_mfma_f32_16x16x32_bf16(al, bl, acc[nt], 0, 0, 0);
        }
    }

    int rbase = r0w + (lane >> 4) * 4;        // D rows this lane owns
    if (rbase >= N) return;
    int4 c4 = *(const int4*)(counts + rbase); // 16B-aligned; alloc slack covers tail
    int cj[4] = {c4.x, c4.y, c4.z, c4.w};
#pragma unroll
    for (int j = 0; j < 4; ++j) {
        int row = rbase + j;
        if (row < N) {
            float di = rsqrtf((float)(cj[j] + 1));
            __half* hp = hn + (size_t)row * HID + (lane & 15);
#pragma unroll
            for (int nt = 0; nt < 4; ++nt)
                hp[nt * 16] = __float2half_rn(acc[nt][j] * di);
        }
    }
}

// ---------------- layer 1 gather (fp16 rows) + self-loop + bias + ReLU + @W2 ----------------
// 2 nodes/wave (32 lanes each), 8 lanes x 16B (dwordx4) per 128B fp16 row, 4 edge groups
// per node. Branchless first 16 edges; wave-uniform guard for 16..32; rare uniform tail.
__device__ inline void accum8(float acc[8], int4 raw, float w) {
    int v[4] = { raw.x, raw.y, raw.z, raw.w };
#pragma unroll
    for (int h = 0; h < 4; ++h) {
        __half2 h2 = *(__half2*)&v[h];
        float2 f = __half22float2(h2);
        acc[2 * h]     = fmaf(w, f.x, acc[2 * h]);
        acc[2 * h + 1] = fmaf(w, f.y, acc[2 * h + 1]);
    }
}

__launch_bounds__(256)
__global__ void k_gather1(const int* __restrict__ csrc, const int* __restrict__ counts,
                          const __half* __restrict__ hn, const float* __restrict__ b1,
                          const float* __restrict__ W2, float* __restrict__ zn, int N) {
    int lane = threadIdx.x & 63;
    int g    = (lane >> 3) & 3;    // edge group 0..3 within the node's 32 lanes
    int li   = lane & 7;           // 16B chunk within the 128B fp16 row
    // node: wave handles 2 nodes; lanes 0-31 -> node A, 32-63 -> node B
    int r = blockIdx.x * 8 + ((threadIdx.x >> 6) << 1) + (lane >> 5);
    int rr = (r < N) ? r : (N - 1);              // clamp: keep all lanes active (shfl safety)
    int cnt = (r < N) ? counts[rr] : 0;          // true degree (for dinv)
    int cw  = (cnt > CAP) ? CAP : cnt;           // clamped (for slot iteration)

    const int4* cs4 = (const int4*)(csrc + (size_t)rr * CAP);  // 16B-aligned
    size_t lo = (size_t)li * 8;   // half offset within the 64-half row (li*16 bytes)

    float acc[8];
#pragma unroll
    for (int c = 0; c < 8; ++c) acc[c] = 0.f;

    // ---- chunk A: edges 4g+k, k=0..3 (covers 0..15) — fully branchless ----
    {
        int4 sA = cs4[g];
        int idx[4]; float w[4];
        idx[0] = sA.x; idx[1] = sA.y; idx[2] = sA.z; idx[3] = sA.w;
#pragma unroll
        for (int k = 0; k < 4; ++k) {
            int e = 4 * g + k;
            bool v = (e < cw);
            idx[k] = v ? idx[k] : rr;   // invalid: own row (cached), weight 0
            w[k]   = v ? 1.f : 0.f;
        }
        int4 raw[4];
#pragma unroll
        for (int k = 0; k < 4; ++k)
            raw[k] = *(const int4*)&hn[(size_t)idx[k] * HID + lo];
#pragma unroll
        for (int k = 0; k < 4; ++k) accum8(acc, raw[k], w[k]);
    }

    // wave-uniform upper bound over both nodes -> scalar branches below
    int cntO = __shfl_xor(cw, 32, 64);
    int cmax = (cw > cntO) ? cw : cntO;

    // ---- chunk B: edges 16+4g+k (covers 16..31), skipped by ~32% of waves ----
    if (cmax > 16) {
        int4 sB = cs4[4 + g];
        int idx[4]; float w[4];
        idx[0] = sB.x; idx[1] = sB.y; idx[2] = sB.z; idx[3] = sB.w;
#pragma unroll
        for (int k = 0; k < 4; ++k) {
            int e = 16 + 4 * g + k;
            bool v = (e < cw);
            idx[k] = v ? idx[k] : rr;
            w[k]   = v ? 1.f : 0.f;
        }
        int4 raw[4];
#pragma unroll
        for (int k = 0; k < 4; ++k)
            raw[k] = *(const int4*)&hn[(size_t)idx[k] * HID + lo];
#pragma unroll
        for (int k = 0; k < 4; ++k) accum8(acc, raw[k], w[k]);
    }

    // ---- rare tail: deg > 32 (Poisson(16) tail ~1e-4), uniform loop ----
    for (int c = 32; c < cmax; c += 16) {
        int4 s = cs4[(c >> 2) + g];
        int idx[4]; float w[4];
        idx[0] = s.x; idx[1] = s.y; idx[2] = s.z; idx[3] = s.w;
#pragma unroll
        for (int k = 0; k < 4; ++k) {
            int e = c + 4 * g + k;
            bool v = (e < cw);
            idx[k] = v ? idx[k] : rr;
            w[k]   = v ? 1.f : 0.f;
        }
        int4 raw[4];
#pragma unroll
        for (int k = 0; k < 4; ++k)
            raw[k] = *(const int4*)&hn[(size_t)idx[k] * HID + lo];
#pragma unroll
        for (int k = 0; k < 4; ++k) accum8(acc, raw[k], w[k]);
    }

    // ---- reduce across the 4 edge groups (lane bits 3..4; stays within each 32-half) ----
#pragma unroll
    for (int c = 0; c < 8; ++c) {
        acc[c] += __shfl_xor(acc[c], 8, 64);
        acc[c] += __shfl_xor(acc[c], 16, 64);
    }

    // ---- self-loop row + bias + ReLU + dot with W2 ----
    int4 rawR = *(const int4*)&hn[(size_t)rr * HID + lo];
    accum8(acc, rawR, 1.f);

    float di = rsqrtf((float)(cnt + 1));
    float4 b0 = *(const float4*)&b1[li * 8];
    float4 b4 = *(const float4*)&b1[li * 8 + 4];
    float4 w0 = *(const float4*)&W2[li * 8];
    float4 w4 = *(const float4*)&W2[li * 8 + 4];

    float p = fmaxf(fmaf(di, acc[0], b0.x), 0.f) * w0.x
            + fmaxf(fmaf(di, acc[1], b0.y), 0.f) * w0.y
            + fmaxf(fmaf(di, acc[2], b0.z), 0.f) * w0.z
            + fmaxf(fmaf(di, acc[3], b0.w), 0.f) * w0.w
            + fmaxf(fmaf(di, acc[4], b4.x), 0.f) * w4.x
            + fmaxf(fmaf(di, acc[5], b4.y), 0.f) * w4.y
            + fmaxf(fmaf(di, acc[6], b4.z), 0.f) * w4.z
            + fmaxf(fmaf(di, acc[7], b4.w), 0.f) * w4.w;

    // sum over the 8 li-lanes (bits 0..2; stays within each 32-half)
    p += __shfl_xor(p, 1, 64);
    p += __shfl_xor(p, 2, 64);
    p += __shfl_xor(p, 4, 64);

    if ((lane & 31) == 0 && r < N) zn[r] = p * di;
}

// ---------------- layer 2 gather: 16 lanes per node ----------------
__global__ void k_gather2(const int* __restrict__ csrc, const int* __restrict__ counts,
                          const float* __restrict__ zn, const float* __restrict__ b2,
                          float* __restrict__ out, int N) {
    int t = blockIdx.x * blockDim.x + threadIdx.x;
    int r = t >> 4, li = t & 15;
    if (r >= N) return;
    size_t beg = (size_t)r * CAP;
    int cnt = counts[r];                     // true degree (for dinv)
    int cw  = (cnt > CAP) ? CAP : cnt;       // clamped (for slot iteration)
    float acc = 0.f;
    for (int j = li; j < cw; j += 16) {
        acc += zn[csrc[beg + j]];
    }
    acc += __shfl_xor(acc, 1, 64);
    acc += __shfl_xor(acc, 2, 64);
    acc += __shfl_xor(acc, 4, 64);
    acc += __shfl_xor(acc, 8, 64);
    if (li == 0) {
        float di = rsqrtf((float)(cnt + 1));
        out[r] = di * (acc + zn[r]) + b2[0];
    }
}

extern "C" void kernel_launch(void* const* d_in, const int* in_sizes, int n_in,
                              void* d_out, int out_size, void* d_ws, size_t ws_size,
                              hipStream_t stream) {
    const float* x  = (const float*)d_in[0];
    const int*   ei = (const int*)d_in[1];   // [2, E] int32
    const float* W1 = (const float*)d_in[2];
    const float* b1 = (const float*)d_in[3];
    const float* W2 = (const float*)d_in[4];
    const float* b2 = (const float*)d_in[5];
    float* out = (float*)d_out;

    const int N = in_sizes[0] / F_IN;     // 100000
    const int E = in_sizes[1] / 2;        // 1600000
    const int* src = ei;
    const int* dst = ei + E;

    const int NBKT = (N + 63) / 64;             // 1563 gemm blocks

    // workspace layout (all 256B-aligned)
    char* ws = (char*)d_ws;
    size_t off = 0;
    auto alloc = [&](size_t bytes) { void* p = ws + off; off += (bytes + 255) & ~255ULL; return p; };
    int*    counts = (int*)   alloc((size_t)N * 4 + 256);     // +slack for int4 tail read
    float*  zn     = (float*) alloc((size_t)N * 4);
    unsigned short* W1hT = (unsigned short*) alloc((size_t)HID * F_IN * 2);  // 16 KB
    unsigned short* W1lT = (unsigned short*) alloc((size_t)HID * F_IN * 2);  // 16 KB
    __half* hn     = (__half*)alloc((size_t)N * HID * 2);     // 12.8 MB
    int*    csrc   = (int*)   alloc((size_t)N * CAP * 4);     // 38.4 MB

    hipMemsetAsync(counts, 0, (size_t)N * 4, stream);

    k_wsplit<<<16, 512, 0, stream>>>(W1, W1hT, W1lT);
    k_scatter<<<(E + 1023) / 1024, 256, 0, stream>>>(src, dst, counts, csrc, E);
    k_gemm<<<NBKT, 256, 0, stream>>>(x, W1hT, W1lT, counts, hn, N);
    k_gather1<<<(N + 7) / 8, 256, 0, stream>>>(csrc, counts, hn, b1, W2, zn, N);
    k_gather2<<<((size_t)N * 16 + 255) / 256, 256, 0, stream>>>(csrc, counts, zn, b2, out, N);
}

// Round 11
// 265.176 us; speedup vs baseline: 1.0708x; 1.0708x over previous
//
#include <hip/hip_runtime.h>
#include <hip/hip_fp16.h>

#define F_IN 128
#define HID  64
#define CAP  96      // max neighbors stored per node (deg ~Poisson(16), max ~45)
#define CSHIFT 7     // coarse bucket = dst >> 7 (128 nodes per bucket)
#define CNODES 128
#define NC_MAX 1024  // >= ceil(N/128)
#define CCHUNK 2048  // edges per coarse-bin block (4 per thread, kept in registers)
#define BCAPC 2560   // entries per coarse bucket (mean 2048, +8 sigma ~2410)

typedef short s16x8 __attribute__((ext_vector_type(8)));   // 8 bf16 (4 VGPRs) MFMA operand
typedef float f32x4 __attribute__((ext_vector_type(4)));   // MFMA accumulator

// bf16 round-to-nearest-even, pure int ops
__device__ inline unsigned short bf16rne(float f) {
    unsigned u = __float_as_uint(f);
    return (unsigned short)((u + 0x7FFFu + ((u >> 16) & 1u)) >> 16);
}
__device__ inline float bf16tof(unsigned short h) {
    return __uint_as_float(((unsigned)h) << 16);
}

// ---------------- W1 split: fp32 [128][64] -> two bf16 transposed copies [64][128] ----------------
__launch_bounds__(512)
__global__ void k_wsplit(const float* __restrict__ W1, unsigned short* __restrict__ W1hT,
                         unsigned short* __restrict__ W1lT) {
    int id = blockIdx.x * 512 + threadIdx.x;   // 0..8191 ; id = k*64 + c
    int k = id >> 6, c = id & 63;
    float f = W1[id];
    unsigned short h = bf16rne(f);
    unsigned short l = bf16rne(f - bf16tof(h));
    W1hT[c * F_IN + k] = h;
    W1lT[c * F_IN + k] = l;
}

// ---------------- Pass A: coarse bin (782 buckets) + per-node degree counts ----------------
// 512 threads x 4 edges in registers (single pass). Bucket-contiguous ent writes (the
// 2-pass scheme that avoids R10's 97MB write amplification). counts via fire-and-forget
// global atomics on the 400KB L2-resident table (cheap; R10 showed the WRITES were the
// expensive half of direct scatter, not these atomics). counts feed gemm's dinv.
__launch_bounds__(512)
__global__ void k_coarse(const int* __restrict__ src, const int* __restrict__ dst,
                         int* __restrict__ acur, int* __restrict__ counts,
                         int* __restrict__ ent, int E, int nc) {
    __shared__ int s_cnt[NC_MAX];
    __shared__ int s_gb[NC_MAX];
    int t = threadIdx.x;
    int e0 = blockIdx.x * CCHUNK;

    for (int i = t; i < nc; i += 512) s_cnt[i] = 0;
    __syncthreads();

    // load 4 edges into registers (coalesced: e = e0 + t + k*512)
    int d0 = 0, d1 = 0, d2 = 0, d3 = 0, s0 = 0, s1 = 0, s2 = 0, s3 = 0;
    int n = E - e0;
    bool v0 = (t        < n), v1 = (t + 512  < n),
         v2 = (t + 1024 < n), v3 = (t + 1536 < n);
    if (v0) { d0 = dst[e0 + t];        s0 = src[e0 + t]; }
    if (v1) { d1 = dst[e0 + t + 512];  s1 = src[e0 + t + 512]; }
    if (v2) { d2 = dst[e0 + t + 1024]; s2 = src[e0 + t + 1024]; }
    if (v3) { d3 = dst[e0 + t + 1536]; s3 = src[e0 + t + 1536]; }

    // per-node degree (fire-and-forget, no return value -> no waitcnt dependency)
    if (v0) atomicAdd(&counts[d0], 1);
    if (v1) atomicAdd(&counts[d1], 1);
    if (v2) atomicAdd(&counts[d2], 1);
    if (v3) atomicAdd(&counts[d3], 1);

    // bucket histogram from registers
    if (v0) atomicAdd(&s_cnt[d0 >> CSHIFT], 1);
    if (v1) atomicAdd(&s_cnt[d1 >> CSHIFT], 1);
    if (v2) atomicAdd(&s_cnt[d2 >> CSHIFT], 1);
    if (v3) atomicAdd(&s_cnt[d3 >> CSHIFT], 1);
    __syncthreads();

    // reserve global runs; s_gb becomes the live cursor
    for (int i = t; i < nc; i += 512) {
        int c = s_cnt[i];
        s_gb[i] = (c > 0) ? atomicAdd(&acur[i], c) : 0;
    }
    __syncthreads();

    // scatter from registers (bucket-contiguous -> lines merge in L2)
    if (v0) { int b = d0 >> CSHIFT; int p = atomicAdd(&s_gb[b], 1);
              if (p < BCAPC) ent[(size_t)b * BCAPC + p] = (s0 << CSHIFT) | (d0 & (CNODES - 1)); }
    if (v1) { int b = d1 >> CSHIFT; int p = atomicAdd(&s_gb[b], 1);
              if (p < BCAPC) ent[(size_t)b * BCAPC + p] = (s1 << CSHIFT) | (d1 & (CNODES - 1)); }
    if (v2) { int b = d2 >> CSHIFT; int p = atomicAdd(&s_gb[b], 1);
              if (p < BCAPC) ent[(size_t)b * BCAPC + p] = (s2 << CSHIFT) | (d2 & (CNODES - 1)); }
    if (v3) { int b = d3 >> CSHIFT; int p = atomicAdd(&s_gb[b], 1);
              if (p < BCAPC) ent[(size_t)b * BCAPC + p] = (s3 << CSHIFT) | (d3 & (CNODES - 1)); }
}

// ---------------- GEMM via MFMA: hn = fp16( (x @ W1) * dinv(row) ) ----------------
// (round-6 form: no LDS, no barriers; measured best of the three gemm engines)
__launch_bounds__(256)
__global__ void k_gemm(const float* __restrict__ x,
                       const unsigned short* __restrict__ W1hT,
                       const unsigned short* __restrict__ W1lT,
                       const int* __restrict__ counts, __half* __restrict__ hn, int N) {
    int t = threadIdx.x;
    int lane = t & 63;
    int wid = t >> 6;
    int r0w = blockIdx.x * 64 + wid * 16;     // wave's 16-row base
    int arow = r0w + (lane & 15);
    int ar = (arow < N) ? arow : (N - 1);     // clamp; out-of-range rows never stored
    int kq = lane >> 4;                        // k-quarter 0..3

    const float* xr = x + (size_t)ar * F_IN + kq * 8;
    int coff = (lane & 15) * F_IN + kq * 8;    // elem offset in [col][k] bf16 layout

    f32x4 acc[4];
#pragma unroll
    for (int nt = 0; nt < 4; ++nt) acc[nt] = (f32x4){0.f, 0.f, 0.f, 0.f};

#pragma unroll
    for (int kt = 0; kt < 4; ++kt) {
        float4 xa = *(const float4*)(xr + kt * 32);
        float4 xb = *(const float4*)(xr + kt * 32 + 4);
        float xf[8] = {xa.x, xa.y, xa.z, xa.w, xb.x, xb.y, xb.z, xb.w};
        s16x8 ah, al;
#pragma unroll
        for (int j = 0; j < 8; ++j) {
            unsigned short h = bf16rne(xf[j]);
            ah[j] = (short)h;
            al[j] = (short)bf16rne(xf[j] - bf16tof(h));
        }
        int kb = coff + kt * 32;
#pragma unroll
        for (int nt = 0; nt < 4; ++nt) {
            s16x8 bh = *(const s16x8*)(W1hT + nt * 16 * F_IN + kb);
            s16x8 bl = *(const s16x8*)(W1lT + nt * 16 * F_IN + kb);
            acc[nt] = __builtin_amdgcn_mfma_f32_16x16x32_bf16(ah, bh, acc[nt], 0, 0, 0);
            acc[nt] = __builtin_amdgcn_mfma_f32_16x16x32_bf16(al, bh, acc[nt], 0, 0, 0);
            acc[nt] = __builtin_amdgcn_mfma_f32_16x16x32_bf16(ah, bl, acc[nt], 0, 0, 0);
            acc[nt] = __builtin_amdgcn_mfma_f32_16x16x32_bf16(al, bl, acc[nt], 0, 0, 0);
        }
    }

    int rbase = r0w + (lane >> 4) * 4;        // D rows this lane owns
    if (rbase >= N) return;
    int4 c4 = *(const int4*)(counts + rbase); // 16B-aligned; alloc slack covers tail
    int cj[4] = {c4.x, c4.y, c4.z, c4.w};
#pragma unroll
    for (int j = 0; j < 4; ++j) {
        int row = rbase + j;
        if (row < N) {
            float di = rsqrtf((float)(cj[j] + 1));
            __half* hp = hn + (size_t)row * HID + (lane & 15);
#pragma unroll
            for (int nt = 0; nt < 4; ++nt)
                hp[nt * 16] = __float2half_rn(acc[nt][j] * di);
        }
    }
}

// ---------------- FUSED fillc + layer-1 gather: bucket -> LDS neighbor lists -> zn ----------------
// One block per bucket (1024 thr, 49.6KB LDS). Phase 1: LDS-atomic sort of the bucket's
// ent entries into per-node lists (csrc never touches global). Phase 2: proven gather1
// body — 2 nodes/wave x 16 waves x 4 passes; neighbor indices via ds_read_b128.
__device__ inline void accum8(float acc[8], int4 raw, float w) {
    int v[4] = { raw.x, raw.y, raw.z, raw.w };
#pragma unroll
    for (int h = 0; h < 4; ++h) {
        __half2 h2 = *(__half2*)&v[h];
        float2 f = __half22float2(h2);
        acc[2 * h]     = fmaf(w, f.x, acc[2 * h]);
        acc[2 * h + 1] = fmaf(w, f.y, acc[2 * h + 1]);
    }
}

__launch_bounds__(1024)
__global__ void k_fg1(const int* __restrict__ acur, const int* __restrict__ ent,
                      const __half* __restrict__ hn, const float* __restrict__ b1,
                      const float* __restrict__ W2, float* __restrict__ zn, int N) {
    __shared__ int lcnt[CNODES];
    __shared__ int csrcL[CNODES * CAP];   // 49152 B
    int b = blockIdx.x, t = threadIdx.x;
    if (t < CNODES) lcnt[t] = 0;
    __syncthreads();

    int base = b * CNODES;
    int cnt_b = acur[b]; if (cnt_b > BCAPC) cnt_b = BCAPC;
    const int* ep = ent + (size_t)b * BCAPC;
    for (int i = t; i < cnt_b; i += 1024) {
        int v = ep[i];
        int ld = v & (CNODES - 1), s = v >> CSHIFT;
        int p = atomicAdd(&lcnt[ld], 1);
        if (p < CAP) csrcL[ld * CAP + p] = s;
    }
    __syncthreads();

    int lane = t & 63;
    int g    = (lane >> 3) & 3;    // edge group 0..3 within the node's 32 lanes
    int li   = lane & 7;           // 16B chunk within the 128B fp16 row
    int wv   = t >> 6;             // wave 0..15
    size_t lo = (size_t)li * 8;

    float4 b0 = *(const float4*)&b1[li * 8];
    float4 b4 = *(const float4*)&b1[li * 8 + 4];
    float4 w0 = *(const float4*)&W2[li * 8];
    float4 w4 = *(const float4*)&W2[li * 8 + 4];

#pragma unroll
    for (int pass = 0; pass < 4; ++pass) {
        int ld = pass * 32 + wv * 2 + (lane >> 5);   // local node 0..127
        int r  = base + ld;
        int rr = (r < N) ? r : (N - 1);
        int cnt = (r < N) ? lcnt[ld] : 0;            // true degree
        int cw  = (cnt > CAP) ? CAP : cnt;           // stored-list clamp
        const int4* cs4 = (const int4*)&csrcL[ld * CAP];

        float acc[8];
#pragma unroll
        for (int c = 0; c < 8; ++c) acc[c] = 0.f;

        // ---- chunk A: edges 4g+k (covers 0..15) — branchless ----
        {
            int4 sA = cs4[g];
            int idx[4]; float w[4];
            idx[0] = sA.x; idx[1] = sA.y; idx[2] = sA.z; idx[3] = sA.w;
#pragma unroll
            for (int k = 0; k < 4; ++k) {
                int e = 4 * g + k;
                bool v = (e < cw);
                idx[k] = v ? idx[k] : rr;
                w[k]   = v ? 1.f : 0.f;
            }
            int4 raw[4];
#pragma unroll
            for (int k = 0; k < 4; ++k)
                raw[k] = *(const int4*)&hn[(size_t)idx[k] * HID + lo];
#pragma unroll
            for (int k = 0; k < 4; ++k) accum8(acc, raw[k], w[k]);
        }

        // wave-uniform bound over the wave's two nodes
        int cntO = __shfl_xor(cw, 32, 64);
        int cmax = (cw > cntO) ? cw : cntO;

        // ---- chunk B: edges 16..31 ----
        if (cmax > 16) {
            int4 sB = cs4[4 + g];
            int idx[4]; float w[4];
            idx[0] = sB.x; idx[1] = sB.y; idx[2] = sB.z; idx[3] = sB.w;
#pragma unroll
            for (int k = 0; k < 4; ++k) {
                int e = 16 + 4 * g + k;
                bool v = (e < cw);
                idx[k] = v ? idx[k] : rr;
                w[k]   = v ? 1.f : 0.f;
            }
            int4 raw[4];
#pragma unroll
            for (int k = 0; k < 4; ++k)
                raw[k] = *(const int4*)&hn[(size_t)idx[k] * HID + lo];
#pragma unroll
            for (int k = 0; k < 4; ++k) accum8(acc, raw[k], w[k]);
        }

        // ---- rare tail: deg > 32 ----
        for (int c = 32; c < cmax; c += 16) {
            int4 s = cs4[(c >> 2) + g];
            int idx[4]; float w[4];
            idx[0] = s.x; idx[1] = s.y; idx[2] = s.z; idx[3] = s.w;
#pragma unroll
            for (int k = 0; k < 4; ++k) {
                int e = c + 4 * g + k;
                bool v = (e < cw);
                idx[k] = v ? idx[k] : rr;
                w[k]   = v ? 1.f : 0.f;
            }
            int4 raw[4];
#pragma unroll
            for (int k = 0; k < 4; ++k)
                raw[k] = *(const int4*)&hn[(size_t)idx[k] * HID + lo];
#pragma unroll
            for (int k = 0; k < 4; ++k) accum8(acc, raw[k], w[k]);
        }

        // ---- reduce across the 4 edge groups (lane bits 3..4) ----
#pragma unroll
        for (int c = 0; c < 8; ++c) {
            acc[c] += __shfl_xor(acc[c], 8, 64);
            acc[c] += __shfl_xor(acc[c], 16, 64);
        }

        // ---- self-loop + bias + ReLU + dot with W2 ----
        int4 rawR = *(const int4*)&hn[(size_t)rr * HID + lo];
        accum8(acc, rawR, 1.f);

        float di = rsqrtf((float)(cnt + 1));
        float p = fmaxf(fmaf(di, acc[0], b0.x), 0.f) * w0.x
                + fmaxf(fmaf(di, acc[1], b0.y), 0.f) * w0.y
                + fmaxf(fmaf(di, acc[2], b0.z), 0.f) * w0.z
                + fmaxf(fmaf(di, acc[3], b0.w), 0.f) * w0.w
                + fmaxf(fmaf(di, acc[4], b4.x), 0.f) * w4.x
                + fmaxf(fmaf(di, acc[5], b4.y), 0.f) * w4.y
                + fmaxf(fmaf(di, acc[6], b4.z), 0.f) * w4.z
                + fmaxf(fmaf(di, acc[7], b4.w), 0.f) * w4.w;

        p += __shfl_xor(p, 1, 64);
        p += __shfl_xor(p, 2, 64);
        p += __shfl_xor(p, 4, 64);

        if ((lane & 31) == 0 && r < N) zn[r] = p * di;
    }
}

// ---------------- layer 2: edge-parallel from ent, LDS accumulators ----------------
// One block per bucket: accum[d&127] += zn[s] via LDS float atomics (~2086 edges/block),
// then out = dinv*(accum + zn[self]) + b2. csrc is never needed.
__launch_bounds__(256)
__global__ void k_g2e(const int* __restrict__ acur, const int* __restrict__ ent,
                      const int* __restrict__ counts, const float* __restrict__ zn,
                      const float* __restrict__ b2, float* __restrict__ out, int N) {
    __shared__ float accum[CNODES];
    int b = blockIdx.x, t = threadIdx.x;
    if (t < CNODES) accum[t] = 0.f;
    __syncthreads();
    int base = b * CNODES;
    int cnt_b = acur[b]; if (cnt_b > BCAPC) cnt_b = BCAPC;
    const int* ep = ent + (size_t)b * BCAPC;
    for (int i = t; i < cnt_b; i += 256) {
        int v = ep[i];
        atomicAdd(&accum[v & (CNODES - 1)], zn[v >> CSHIFT]);
    }
    __syncthreads();
    if (t < CNODES) {
        int node = base + t;
        if (node < N) {
            float di = rsqrtf((float)(counts[node] + 1));
            out[node] = di * (accum[t] + zn[node]) + b2[0];
        }
    }
}

extern "C" void kernel_launch(void* const* d_in, const int* in_sizes, int n_in,
                              void* d_out, int out_size, void* d_ws, size_t ws_size,
                              hipStream_t stream) {
    const float* x  = (const float*)d_in[0];
    const int*   ei = (const int*)d_in[1];   // [2, E] int32
    const float* W1 = (const float*)d_in[2];
    const float* b1 = (const float*)d_in[3];
    const float* W2 = (const float*)d_in[4];
    const float* b2 = (const float*)d_in[5];
    float* out = (float*)d_out;

    const int N = in_sizes[0] / F_IN;     // 100000
    const int E = in_sizes[1] / 2;        // 1600000
    const int* src = ei;
    const int* dst = ei + E;

    const int nc = (N + CNODES - 1) / CNODES;   // 782 coarse buckets
    const int NBKT = (N + 63) / 64;             // 1563 gemm blocks

    // workspace layout (all 256B-aligned); acur+counts adjacent -> one memset
    char* ws = (char*)d_ws;
    size_t off = 0;
    auto alloc = [&](size_t bytes) { void* p = ws + off; off += (bytes + 255) & ~255ULL; return p; };
    int*    acur   = (int*)   alloc((size_t)nc * 4);
    int*    counts = (int*)   alloc((size_t)N * 4 + 256);     // +slack for int4 tail read
    float*  zn     = (float*) alloc((size_t)N * 4);
    unsigned short* W1hT = (unsigned short*) alloc((size_t)HID * F_IN * 2);  // 16 KB
    unsigned short* W1lT = (unsigned short*) alloc((size_t)HID * F_IN * 2);  // 16 KB
    int*    ent    = (int*)   alloc((size_t)nc * BCAPC * 4);  // 8.0 MB
    __half* hn     = (__half*)alloc((size_t)N * HID * 2);     // 12.8 MB

    // zero acur..counts span in one call (they are adjacent)
    size_t zspan = (size_t)((char*)counts - (char*)acur) + (size_t)N * 4;
    hipMemsetAsync(acur, 0, zspan, stream);

    const int coarseBlks = (E + CCHUNK - 1) / CCHUNK;   // 782
    k_wsplit<<<16, 512, 0, stream>>>(W1, W1hT, W1lT);
    k_coarse<<<coarseBlks, 512, 0, stream>>>(src, dst, acur, counts, ent, E, nc);
    k_gemm<<<NBKT, 256, 0, stream>>>(x, W1hT, W1lT, counts, hn, N);
    k_fg1<<<nc, 1024, 0, stream>>>(acur, ent, hn, b1, W2, zn, N);
    k_g2e<<<nc, 256, 0, stream>>>(acur, ent, counts, zn, b2, out, N);
}

// Round 12
// 220.964 us; speedup vs baseline: 1.2851x; 1.2001x over previous
//
#include <hip/hip_runtime.h>
#include <hip/hip_fp16.h>

#define F_IN 128
#define HID  64
#define CAP  96      // max edges per dst node (degrees ~Poisson(16), max ~45)
#define CSHIFT 7     // coarse bucket = dst >> 7 (128 nodes per bucket)
#define CNODES 128
#define NC_MAX 1024  // >= ceil(N/128)
#define CCHUNK 2048  // edges per coarse-bin block (4 per thread, kept in registers)
#define BCAPC 2560   // entries per coarse bucket (mean 2086, +8 sigma ~2454)

typedef short s16x8 __attribute__((ext_vector_type(8)));   // 8 bf16 (4 VGPRs) MFMA operand
typedef float f32x4 __attribute__((ext_vector_type(4)));   // MFMA accumulator

// bf16 round-to-nearest-even, pure int ops
__device__ inline unsigned short bf16rne(float f) {
    unsigned u = __float_as_uint(f);
    return (unsigned short)((u + 0x7FFFu + ((u >> 16) & 1u)) >> 16);
}
__device__ inline float bf16tof(unsigned short h) {
    return __uint_as_float(((unsigned)h) << 16);
}

// ---------------- Pass A: coarse bin (782 buckets), single-pass, register-held edges ----------------
// NO per-node counts atomics here (R11 lesson: device-scope random atomics cost ~46us).
// First 16 blocks also perform the W1 hi/lo bf16 split (folded-in; saves a launch).
__launch_bounds__(512)
__global__ void k_coarse(const int* __restrict__ src, const int* __restrict__ dst,
                         int* __restrict__ acur, int* __restrict__ ent, int E, int nc,
                         const float* __restrict__ W1, unsigned short* __restrict__ W1hT,
                         unsigned short* __restrict__ W1lT) {
    __shared__ int s_cnt[NC_MAX];
    __shared__ int s_gb[NC_MAX];
    int t = threadIdx.x;

    if (blockIdx.x < 16) {   // W1 split: 16 blocks x 512 threads = 8192 = F_IN*HID
        int id = blockIdx.x * 512 + t;     // id = k*64 + c
        int k = id >> 6, c = id & 63;
        float f = W1[id];
        unsigned short h = bf16rne(f);
        unsigned short l = bf16rne(f - bf16tof(h));
        W1hT[c * F_IN + k] = h;
        W1lT[c * F_IN + k] = l;
    }

    int e0 = blockIdx.x * CCHUNK;

    for (int i = t; i < nc; i += 512) s_cnt[i] = 0;
    __syncthreads();

    // load 4 edges into registers (coalesced: e = e0 + t + k*512)
    int d0 = 0, d1 = 0, d2 = 0, d3 = 0, s0 = 0, s1 = 0, s2 = 0, s3 = 0;
    int n = E - e0;
    bool v0 = (t        < n), v1 = (t + 512  < n),
         v2 = (t + 1024 < n), v3 = (t + 1536 < n);
    if (v0) { d0 = dst[e0 + t];        s0 = src[e0 + t]; }
    if (v1) { d1 = dst[e0 + t + 512];  s1 = src[e0 + t + 512]; }
    if (v2) { d2 = dst[e0 + t + 1024]; s2 = src[e0 + t + 1024]; }
    if (v3) { d3 = dst[e0 + t + 1536]; s3 = src[e0 + t + 1536]; }

    // bucket histogram from registers
    if (v0) atomicAdd(&s_cnt[d0 >> CSHIFT], 1);
    if (v1) atomicAdd(&s_cnt[d1 >> CSHIFT], 1);
    if (v2) atomicAdd(&s_cnt[d2 >> CSHIFT], 1);
    if (v3) atomicAdd(&s_cnt[d3 >> CSHIFT], 1);
    __syncthreads();

    // reserve global runs; s_gb becomes the live cursor
    for (int i = t; i < nc; i += 512) {
        int c = s_cnt[i];
        s_gb[i] = (c > 0) ? atomicAdd(&acur[i], c) : 0;
    }
    __syncthreads();

    // scatter from registers (bucket-contiguous -> lines merge in L2)
    if (v0) { int b = d0 >> CSHIFT; int p = atomicAdd(&s_gb[b], 1);
              if (p < BCAPC) ent[(size_t)b * BCAPC + p] = (s0 << CSHIFT) | (d0 & (CNODES - 1)); }
    if (v1) { int b = d1 >> CSHIFT; int p = atomicAdd(&s_gb[b], 1);
              if (p < BCAPC) ent[(size_t)b * BCAPC + p] = (s1 << CSHIFT) | (d1 & (CNODES - 1)); }
    if (v2) { int b = d2 >> CSHIFT; int p = atomicAdd(&s_gb[b], 1);
              if (p < BCAPC) ent[(size_t)b * BCAPC + p] = (s2 << CSHIFT) | (d2 & (CNODES - 1)); }
    if (v3) { int b = d3 >> CSHIFT; int p = atomicAdd(&s_gb[b], 1);
              if (p < BCAPC) ent[(size_t)b * BCAPC + p] = (s3 << CSHIFT) | (d3 & (CNODES - 1)); }
}

// ---------------- Pass B: per-coarse-bucket regroup into per-node CSR + counts ----------------
__launch_bounds__(1024)
__global__ void k_fillc(const int* __restrict__ acur, const int* __restrict__ ent,
                        int* __restrict__ counts, int* __restrict__ csrc, int N) {
    __shared__ int lcnt[CNODES];
    int b = blockIdx.x, t = threadIdx.x;
    if (t < CNODES) lcnt[t] = 0;
    __syncthreads();
    int base = b * CNODES;
    int cnt = acur[b]; if (cnt > BCAPC) cnt = BCAPC;
    const int* ep = ent + (size_t)b * BCAPC;
    for (int i = t; i < cnt; i += 1024) {
        int v = ep[i];
        int ld = v & (CNODES - 1), s = v >> CSHIFT;
        int p = atomicAdd(&lcnt[ld], 1);
        if (p < CAP) csrc[(size_t)(base + ld) * CAP + p] = s;
    }
    __syncthreads();
    if (t < CNODES && base + t < N) {
        int cc = lcnt[t]; if (cc > CAP) cc = CAP;
        counts[base + t] = cc;
    }
}

// ---------------- GEMM via MFMA, re-gridded for TLP: hn = fp16( (x @ W1) * dinv(row) ) ----------------
// R11 lesson: all gemm engines tied at ~40us because grid was 6250 waves (~6/SIMD).
// New shape: block = 16 rows x 4 waves; each wave owns a 16-col tile (nt = wid fixed).
// Grid 6250 blocks -> 25000 waves (~24/SIMD, 4x TLP). Per-output FP order identical to the
// verified R6 kernel (same splits, same MFMA sequence) -> absmax unchanged.
__launch_bounds__(256, 8)
__global__ void k_gemm(const float* __restrict__ x,
                       const unsigned short* __restrict__ W1hT,
                       const unsigned short* __restrict__ W1lT,
                       const int* __restrict__ counts, __half* __restrict__ hn, int N) {
    int t = threadIdx.x;
    int lane = t & 63;
    int wid = t >> 6;                          // wave's col tile: cols [wid*16, wid*16+16)
    int r0 = blockIdx.x * 16;                  // block's 16-row base
    int lr = lane & 15;
    int q  = lane >> 4;                        // k-quarter 0..3
    int arow = r0 + lr;
    int ar = (arow < N) ? arow : (N - 1);      // clamp; out-of-range rows never stored

    const float* xr = x + (size_t)ar * F_IN + q * 8;
    int coff = lr * F_IN + q * 8;              // elem offset in [col][k] bf16 layout
    const unsigned short* bhp = W1hT + wid * 16 * F_IN + coff;
    const unsigned short* blp = W1lT + wid * 16 * F_IN + coff;

    f32x4 acc = (f32x4){0.f, 0.f, 0.f, 0.f};

#pragma unroll
    for (int kt = 0; kt < 4; ++kt) {
        float4 xa = *(const float4*)(xr + kt * 32);
        float4 xb = *(const float4*)(xr + kt * 32 + 4);
        float xf[8] = {xa.x, xa.y, xa.z, xa.w, xb.x, xb.y, xb.z, xb.w};
        s16x8 ah, al;
#pragma unroll
        for (int j = 0; j < 8; ++j) {
            unsigned short h = bf16rne(xf[j]);
            ah[j] = (short)h;
            al[j] = (short)bf16rne(xf[j] - bf16tof(h));
        }
        s16x8 bh = *(const s16x8*)(bhp + kt * 32);
        s16x8 bl = *(const s16x8*)(blp + kt * 32);
        acc = __builtin_amdgcn_mfma_f32_16x16x32_bf16(ah, bh, acc, 0, 0, 0);
        acc = __builtin_amdgcn_mfma_f32_16x16x32_bf16(al, bh, acc, 0, 0, 0);
        acc = __builtin_amdgcn_mfma_f32_16x16x32_bf16(ah, bl, acc, 0, 0, 0);
        acc = __builtin_amdgcn_mfma_f32_16x16x32_bf16(al, bl, acc, 0, 0, 0);
    }

    int rbase = r0 + q * 4;                    // D rows this lane owns (col = wid*16 + lr)
    if (rbase >= N) return;
    int4 c4 = *(const int4*)(counts + rbase);  // 16B-aligned; alloc slack covers tail
    int cj[4] = {c4.x, c4.y, c4.z, c4.w};
#pragma unroll
    for (int j = 0; j < 4; ++j) {
        int row = rbase + j;
        if (row < N) {
            float di = rsqrtf((float)(cj[j] + 1));
            hn[(size_t)row * HID + wid * 16 + lr] = __float2half_rn(acc[j] * di);
        }
    }
}

// ---------------- layer 1 gather (fp16 rows) + self-loop + bias + ReLU + @W2 ----------------
// 2 nodes/wave (32 lanes each), 8 lanes x 16B (dwordx4) per 128B fp16 row, 4 edge groups.
__device__ inline void accum8(float acc[8], int4 raw, float w) {
    int v[4] = { raw.x, raw.y, raw.z, raw.w };
#pragma unroll
    for (int h = 0; h < 4; ++h) {
        __half2 h2 = *(__half2*)&v[h];
        float2 f = __half22float2(h2);
        acc[2 * h]     = fmaf(w, f.x, acc[2 * h]);
        acc[2 * h + 1] = fmaf(w, f.y, acc[2 * h + 1]);
    }
}

__launch_bounds__(256)
__global__ void k_gather1(const int* __restrict__ csrc, const int* __restrict__ counts,
                          const __half* __restrict__ hn, const float* __restrict__ b1,
                          const float* __restrict__ W2, float* __restrict__ zn, int N) {
    int lane = threadIdx.x & 63;
    int g    = (lane >> 3) & 3;    // edge group 0..3 within the node's 32 lanes
    int li   = lane & 7;           // 16B chunk within the 128B fp16 row
    int r = blockIdx.x * 8 + ((threadIdx.x >> 6) << 1) + (lane >> 5);
    int rr = (r < N) ? r : (N - 1);              // clamp: keep all lanes active (shfl safety)
    int cnt = (r < N) ? counts[rr] : 0;

    const int4* cs4 = (const int4*)(csrc + (size_t)rr * CAP);  // 16B-aligned
    size_t lo = (size_t)li * 8;   // half offset within the 64-half row (li*16 bytes)

    float acc[8];
#pragma unroll
    for (int c = 0; c < 8; ++c) acc[c] = 0.f;

    // ---- chunk A: edges 4g+k, k=0..3 (covers 0..15) — fully branchless ----
    {
        int4 sA = cs4[g];
        int idx[4]; float w[4];
        idx[0] = sA.x; idx[1] = sA.y; idx[2] = sA.z; idx[3] = sA.w;
#pragma unroll
        for (int k = 0; k < 4; ++k) {
            int e = 4 * g + k;
            bool v = (e < cnt);
            idx[k] = v ? idx[k] : rr;   // invalid: own row (cached), weight 0
            w[k]   = v ? 1.f : 0.f;
        }
        int4 raw[4];
#pragma unroll
        for (int k = 0; k < 4; ++k)
            raw[k] = *(const int4*)&hn[(size_t)idx[k] * HID + lo];
#pragma unroll
        for (int k = 0; k < 4; ++k) accum8(acc, raw[k], w[k]);
    }

    // wave-uniform upper bound over both nodes -> scalar branches below
    int cntO = __shfl_xor(cnt, 32, 64);
    int cmax = (cnt > cntO) ? cnt : cntO;

    // ---- chunk B: edges 16+4g+k (covers 16..31), skipped by ~32% of waves ----
    if (cmax > 16) {
        int4 sB = cs4[4 + g];
        int idx[4]; float w[4];
        idx[0] = sB.x; idx[1] = sB.y; idx[2] = sB.z; idx[3] = sB.w;
#pragma unroll
        for (int k = 0; k < 4; ++k) {
            int e = 16 + 4 * g + k;
            bool v = (e < cnt);
            idx[k] = v ? idx[k] : rr;
            w[k]   = v ? 1.f : 0.f;
        }
        int4 raw[4];
#pragma unroll
        for (int k = 0; k < 4; ++k)
            raw[k] = *(const int4*)&hn[(size_t)idx[k] * HID + lo];
#pragma unroll
        for (int k = 0; k < 4; ++k) accum8(acc, raw[k], w[k]);
    }

    // ---- rare tail: deg > 32 (Poisson(16) tail ~1e-4), uniform loop ----
    for (int c = 32; c < cmax; c += 16) {
        int4 s = cs4[(c >> 2) + g];
        int idx[4]; float w[4];
        idx[0] = s.x; idx[1] = s.y; idx[2] = s.z; idx[3] = s.w;
#pragma unroll
        for (int k = 0; k < 4; ++k) {
            int e = c + 4 * g + k;
            bool v = (e < cnt);
            idx[k] = v ? idx[k] : rr;
            w[k]   = v ? 1.f : 0.f;
        }
        int4 raw[4];
#pragma unroll
        for (int k = 0; k < 4; ++k)
            raw[k] = *(const int4*)&hn[(size_t)idx[k] * HID + lo];
#pragma unroll
        for (int k = 0; k < 4; ++k) accum8(acc, raw[k], w[k]);
    }

    // ---- reduce across the 4 edge groups (lane bits 3..4; stays within each 32-half) ----
#pragma unroll
    for (int c = 0; c < 8; ++c) {
        acc[c] += __shfl_xor(acc[c], 8, 64);
        acc[c] += __shfl_xor(acc[c], 16, 64);
    }

    // ---- self-loop row + bias + ReLU + dot with W2 ----
    int4 rawR = *(const int4*)&hn[(size_t)rr * HID + lo];
    accum8(acc, rawR, 1.f);

    float di = rsqrtf((float)(cnt + 1));
    float4 b0 = *(const float4*)&b1[li * 8];
    float4 b4 = *(const float4*)&b1[li * 8 + 4];
    float4 w0 = *(const float4*)&W2[li * 8];
    float4 w4 = *(const float4*)&W2[li * 8 + 4];

    float p = fmaxf(fmaf(di, acc[0], b0.x), 0.f) * w0.x
            + fmaxf(fmaf(di, acc[1], b0.y), 0.f) * w0.y
            + fmaxf(fmaf(di, acc[2], b0.z), 0.f) * w0.z
            + fmaxf(fmaf(di, acc[3], b0.w), 0.f) * w0.w
            + fmaxf(fmaf(di, acc[4], b4.x), 0.f) * w4.x
            + fmaxf(fmaf(di, acc[5], b4.y), 0.f) * w4.y
            + fmaxf(fmaf(di, acc[6], b4.z), 0.f) * w4.z
            + fmaxf(fmaf(di, acc[7], b4.w), 0.f) * w4.w;

    // sum over the 8 li-lanes (bits 0..2; stays within each 32-half)
    p += __shfl_xor(p, 1, 64);
    p += __shfl_xor(p, 2, 64);
    p += __shfl_xor(p, 4, 64);

    if ((lane & 31) == 0 && r < N) zn[r] = p * di;
}

// ---------------- layer 2 gather: 16 lanes per node ----------------
__global__ void k_gather2(const int* __restrict__ csrc, const int* __restrict__ counts,
                          const float* __restrict__ zn, const float* __restrict__ b2,
                          float* __restrict__ out, int N) {
    int t = blockIdx.x * blockDim.x + threadIdx.x;
    int r = t >> 4, li = t & 15;
    if (r >= N) return;
    size_t beg = (size_t)r * CAP;
    int cnt = counts[r];
    float acc = 0.f;
    for (int j = li; j < cnt; j += 16) {
        acc += zn[csrc[beg + j]];
    }
    acc += __shfl_xor(acc, 1, 64);
    acc += __shfl_xor(acc, 2, 64);
    acc += __shfl_xor(acc, 4, 64);
    acc += __shfl_xor(acc, 8, 64);
    if (li == 0) {
        float di = rsqrtf((float)(cnt + 1));
        out[r] = di * (acc + zn[r]) + b2[0];
    }
}

extern "C" void kernel_launch(void* const* d_in, const int* in_sizes, int n_in,
                              void* d_out, int out_size, void* d_ws, size_t ws_size,
                              hipStream_t stream) {
    const float* x  = (const float*)d_in[0];
    const int*   ei = (const int*)d_in[1];   // [2, E] int32
    const float* W1 = (const float*)d_in[2];
    const float* b1 = (const float*)d_in[3];
    const float* W2 = (const float*)d_in[4];
    const float* b2 = (const float*)d_in[5];
    float* out = (float*)d_out;

    const int N = in_sizes[0] / F_IN;     // 100000
    const int E = in_sizes[1] / 2;        // 1600000
    const int* src = ei;
    const int* dst = ei + E;

    const int nc = (N + CNODES - 1) / CNODES;   // 782 coarse buckets
    const int NBKT = (N + 15) / 16;             // 6250 gemm blocks (16 rows each)

    // workspace layout (all 256B-aligned)
    char* ws = (char*)d_ws;
    size_t off = 0;
    auto alloc = [&](size_t bytes) { void* p = ws + off; off += (bytes + 255) & ~255ULL; return p; };
    int*    acur   = (int*)   alloc((size_t)nc * 4);
    int*    counts = (int*)   alloc((size_t)N * 4 + 256);     // +slack for int4 tail read
    float*  zn     = (float*) alloc((size_t)N * 4);
    unsigned short* W1hT = (unsigned short*) alloc((size_t)HID * F_IN * 2);  // 16 KB
    unsigned short* W1lT = (unsigned short*) alloc((size_t)HID * F_IN * 2);  // 16 KB
    int*    ent    = (int*)   alloc((size_t)nc * BCAPC * 4);  // 8.0 MB
    __half* hn     = (__half*)alloc((size_t)N * HID * 2);     // 12.8 MB
    int*    csrc   = (int*)   alloc((size_t)N * CAP * 4);     // 38.4 MB

    hipMemsetAsync(acur, 0, (size_t)nc * 4, stream);

    const int coarseBlks = (E + CCHUNK - 1) / CCHUNK;   // 782
    k_coarse<<<coarseBlks, 512, 0, stream>>>(src, dst, acur, ent, E, nc, W1, W1hT, W1lT);
    k_fillc<<<nc, 1024, 0, stream>>>(acur, ent, counts, csrc, N);
    k_gemm<<<NBKT, 256, 0, stream>>>(x, W1hT, W1lT, counts, hn, N);
    k_gather1<<<(N + 7) / 8, 256, 0, stream>>>(csrc, counts, hn, b1, W2, zn, N);
    k_gather2<<<((size_t)N * 16 + 255) / 256, 256, 0, stream>>>(csrc, counts, zn, b2, out, N);
}

// Round 13
// 192.934 us; speedup vs baseline: 1.4718x; 1.1453x over previous
//
#include <hip/hip_runtime.h>
#include <hip/hip_fp16.h>

#define F_IN 128
#define HID  64
#define CAP  96      // max edges per dst node (degrees ~Poisson(16), max ~45)
#define CSHIFT 9     // coarse bucket = dst >> 9 (512 nodes per bucket)
#define CNODES 512
#define NC_MAX 256   // >= ceil(N/512)
#define CCHUNK 4096  // edges per coarse-bin block (8 per thread, kept in registers)
#define BCAPC 8960   // entries per coarse bucket (mean 8163, +8 sigma)

// ---------------- Pass A: coarse bin (196 buckets), single-pass, register-held edges ----------------
// R12 consolidation: CSHIFT 9 + CCHUNK 4096 preserved (long ~21-edge ent runs -> low write
// amplification, the axis R9's CCHUNK-2048 change destroyed), but 512 threads x 8 edges
// in registers: 12 waves/CU (vs 6) and edges read ONCE (histogram + scatter from regs).
__launch_bounds__(512)
__global__ void k_coarse(const int* __restrict__ src, const int* __restrict__ dst,
                         int* __restrict__ acur, int* __restrict__ ent, int E, int nc) {
    __shared__ int s_cnt[NC_MAX];
    __shared__ int s_gb[NC_MAX];
    int t = threadIdx.x;
    int e0 = blockIdx.x * CCHUNK;

    for (int i = t; i < nc; i += 512) s_cnt[i] = 0;
    __syncthreads();

    // load 8 edges into registers (coalesced: e = e0 + t + k*512)
    int d[8], s[8]; bool v[8];
    int n = E - e0;
#pragma unroll
    for (int k = 0; k < 8; ++k) {
        int e = t + k * 512;
        v[k] = (e < n);
        d[k] = v[k] ? dst[e0 + e] : 0;
        s[k] = v[k] ? src[e0 + e] : 0;
    }

    // bucket histogram from registers
#pragma unroll
    for (int k = 0; k < 8; ++k)
        if (v[k]) atomicAdd(&s_cnt[d[k] >> CSHIFT], 1);
    __syncthreads();

    // reserve global runs; s_gb becomes the live cursor
    for (int i = t; i < nc; i += 512) {
        int c = s_cnt[i];
        s_gb[i] = (c > 0) ? atomicAdd(&acur[i], c) : 0;
    }
    __syncthreads();

    // scatter from registers (per-(block,bucket) runs are contiguous -> lines merge in L2)
#pragma unroll
    for (int k = 0; k < 8; ++k) {
        if (v[k]) {
            int b = d[k] >> CSHIFT;
            int p = atomicAdd(&s_gb[b], 1);
            if (p < BCAPC) ent[(size_t)b * BCAPC + p] = (s[k] << CSHIFT) | (d[k] & (CNODES - 1));
        }
    }
}

// ---------------- Pass B: per-coarse-bucket regroup into per-node CSR ----------------
__launch_bounds__(1024)
__global__ void k_fillc(const int* __restrict__ acur, const int* __restrict__ ent,
                        int* __restrict__ counts, int* __restrict__ csrc, int N) {
    __shared__ int lcnt[CNODES];
    int b = blockIdx.x, t = threadIdx.x;
    if (t < CNODES) lcnt[t] = 0;
    __syncthreads();
    int base = b * CNODES;
    int cnt = acur[b]; if (cnt > BCAPC) cnt = BCAPC;
    const int* ep = ent + (size_t)b * BCAPC;
    for (int i = t; i < cnt; i += 1024) {
        int v = ep[i];
        int ld = v & (CNODES - 1), s = v >> CSHIFT;
        int p = atomicAdd(&lcnt[ld], 1);
        if (p < CAP) csrc[(size_t)(base + ld) * CAP + p] = s;
    }
    __syncthreads();
    if (t < CNODES && base + t < N) {
        int cc = lcnt[t]; if (cc > CAP) cc = CAP;
        counts[base + t] = cc;
    }
}

// ---------------- GEMM: hn = fp16( (x @ W1) * dinv(row) ) ----------------
// R5 form (best measured of all five gemm engines tried: 41.7us).
// LDS-free: lane owns row r0+lane and streams its own x-row via float4 global loads;
// W1 via wave-uniform scalar loads. No staging, no barriers, 8 blocks/CU cap.
__launch_bounds__(256, 8)
__global__ void k_gemm(const float* __restrict__ x, const float* __restrict__ W1,
                       const int* __restrict__ counts, __half* __restrict__ hn, int N) {
    int t = threadIdx.x;
    int lane = t & 63;
    int c0 = __builtin_amdgcn_readfirstlane(t >> 6) * 16;
    int r0 = blockIdx.x * 64;
    int row = r0 + lane;
    int rr = (row < N) ? row : (N - 1);   // clamp; out-of-range result discarded

    const float* xr = x + (size_t)rr * F_IN;

    float acc[16];
#pragma unroll
    for (int c = 0; c < 16; ++c) acc[c] = 0.f;

    for (int k = 0; k < F_IN; k += 4) {
        float4 xv = *(const float4*)&xr[k];
        const float* wr = W1 + (size_t)k * HID + c0;   // wave-uniform -> s_load
#pragma unroll
        for (int c = 0; c < 16; ++c) {
            float a = acc[c];
            a = fmaf(xv.x, wr[c], a);
            a = fmaf(xv.y, wr[HID + c], a);
            a = fmaf(xv.z, wr[2 * HID + c], a);
            a = fmaf(xv.w, wr[3 * HID + c], a);
            acc[c] = a;
        }
    }

    if (row < N) {
        float di = rsqrtf((float)(counts[row] + 1));
        __half* hp = hn + (size_t)row * HID + c0;
        unsigned int us[8];
#pragma unroll
        for (int c = 0; c < 16; c += 2) {
            __half2 h2 = __floats2half2_rn(acc[c] * di, acc[c + 1] * di);
            us[c >> 1] = *(unsigned int*)&h2;
        }
        *(uint4*)&hp[0] = make_uint4(us[0], us[1], us[2], us[3]);
        *(uint4*)&hp[8] = make_uint4(us[4], us[5], us[6], us[7]);
    }
}

// ---------------- layer 1 gather (fp16 rows) + self-loop + bias + ReLU + @W2 ----------------
// 2 nodes/wave (32 lanes each), 8 lanes x 16B (dwordx4) per 128B fp16 row, 4 edge groups
// per node. Branchless first 16 edges; wave-uniform guard for 16..32; rare uniform tail.
__device__ inline void accum8(float acc[8], int4 raw, float w) {
    int v[4] = { raw.x, raw.y, raw.z, raw.w };
#pragma unroll
    for (int h = 0; h < 4; ++h) {
        __half2 h2 = *(__half2*)&v[h];
        float2 f = __half22float2(h2);
        acc[2 * h]     = fmaf(w, f.x, acc[2 * h]);
        acc[2 * h + 1] = fmaf(w, f.y, acc[2 * h + 1]);
    }
}

__launch_bounds__(256)
__global__ void k_gather1(const int* __restrict__ csrc, const int* __restrict__ counts,
                          const __half* __restrict__ hn, const float* __restrict__ b1,
                          const float* __restrict__ W2, float* __restrict__ zn, int N) {
    int lane = threadIdx.x & 63;
    int g    = (lane >> 3) & 3;    // edge group 0..3 within the node's 32 lanes
    int li   = lane & 7;           // 16B chunk within the 128B fp16 row
    // node: wave handles 2 nodes; lanes 0-31 -> node A, 32-63 -> node B
    int r = blockIdx.x * 8 + ((threadIdx.x >> 6) << 1) + (lane >> 5);
    int rr = (r < N) ? r : (N - 1);              // clamp: keep all lanes active (shfl safety)
    int cnt = (r < N) ? counts[rr] : 0;

    const int4* cs4 = (const int4*)(csrc + (size_t)rr * CAP);  // 16B-aligned
    size_t lo = (size_t)li * 8;   // half offset within the 64-half row (li*16 bytes)

    float acc[8];
#pragma unroll
    for (int c = 0; c < 8; ++c) acc[c] = 0.f;

    // ---- chunk A: edges 4g+k, k=0..3 (covers 0..15) — fully branchless ----
    {
        int4 sA = cs4[g];
        int idx[4]; float w[4];
        idx[0] = sA.x; idx[1] = sA.y; idx[2] = sA.z; idx[3] = sA.w;
#pragma unroll
        for (int k = 0; k < 4; ++k) {
            int e = 4 * g + k;
            bool v = (e < cnt);
            idx[k] = v ? idx[k] : rr;   // invalid: own row (cached), weight 0
            w[k]   = v ? 1.f : 0.f;
        }
        int4 raw[4];
#pragma unroll
        for (int k = 0; k < 4; ++k)
            raw[k] = *(const int4*)&hn[(size_t)idx[k] * HID + lo];
#pragma unroll
        for (int k = 0; k < 4; ++k) accum8(acc, raw[k], w[k]);
    }

    // wave-uniform upper bound over both nodes -> scalar branches below
    int cntO = __shfl_xor(cnt, 32, 64);
    int cmax = (cnt > cntO) ? cnt : cntO;

    // ---- chunk B: edges 16+4g+k (covers 16..31), skipped by ~32% of waves ----
    if (cmax > 16) {
        int4 sB = cs4[4 + g];
        int idx[4]; float w[4];
        idx[0] = sB.x; idx[1] = sB.y; idx[2] = sB.z; idx[3] = sB.w;
#pragma unroll
        for (int k = 0; k < 4; ++k) {
            int e = 16 + 4 * g + k;
            bool v = (e < cnt);
            idx[k] = v ? idx[k] : rr;
            w[k]   = v ? 1.f : 0.f;
        }
        int4 raw[4];
#pragma unroll
        for (int k = 0; k < 4; ++k)
            raw[k] = *(const int4*)&hn[(size_t)idx[k] * HID + lo];
#pragma unroll
        for (int k = 0; k < 4; ++k) accum8(acc, raw[k], w[k]);
    }

    // ---- rare tail: deg > 32 (Poisson(16) tail ~1e-4), uniform loop ----
    for (int c = 32; c < cmax; c += 16) {
        int4 s = cs4[(c >> 2) + g];
        int idx[4]; float w[4];
        idx[0] = s.x; idx[1] = s.y; idx[2] = s.z; idx[3] = s.w;
#pragma unroll
        for (int k = 0; k < 4; ++k) {
            int e = c + 4 * g + k;
            bool v = (e < cnt);
            idx[k] = v ? idx[k] : rr;
            w[k]   = v ? 1.f : 0.f;
        }
        int4 raw[4];
#pragma unroll
        for (int k = 0; k < 4; ++k)
            raw[k] = *(const int4*)&hn[(size_t)idx[k] * HID + lo];
#pragma unroll
        for (int k = 0; k < 4; ++k) accum8(acc, raw[k], w[k]);
    }

    // ---- reduce across the 4 edge groups (lane bits 3..4; stays within each 32-half) ----
#pragma unroll
    for (int c = 0; c < 8; ++c) {
        acc[c] += __shfl_xor(acc[c], 8, 64);
        acc[c] += __shfl_xor(acc[c], 16, 64);
    }

    // ---- self-loop row + bias + ReLU + dot with W2 ----
    int4 rawR = *(const int4*)&hn[(size_t)rr * HID + lo];
    accum8(acc, rawR, 1.f);

    float di = rsqrtf((float)(cnt + 1));
    float4 b0 = *(const float4*)&b1[li * 8];
    float4 b4 = *(const float4*)&b1[li * 8 + 4];
    float4 w0 = *(const float4*)&W2[li * 8];
    float4 w4 = *(const float4*)&W2[li * 8 + 4];

    float p = fmaxf(fmaf(di, acc[0], b0.x), 0.f) * w0.x
            + fmaxf(fmaf(di, acc[1], b0.y), 0.f) * w0.y
            + fmaxf(fmaf(di, acc[2], b0.z), 0.f) * w0.z
            + fmaxf(fmaf(di, acc[3], b0.w), 0.f) * w0.w
            + fmaxf(fmaf(di, acc[4], b4.x), 0.f) * w4.x
            + fmaxf(fmaf(di, acc[5], b4.y), 0.f) * w4.y
            + fmaxf(fmaf(di, acc[6], b4.z), 0.f) * w4.z
            + fmaxf(fmaf(di, acc[7], b4.w), 0.f) * w4.w;

    // sum over the 8 li-lanes (bits 0..2; stays within each 32-half)
    p += __shfl_xor(p, 1, 64);
    p += __shfl_xor(p, 2, 64);
    p += __shfl_xor(p, 4, 64);

    if ((lane & 31) == 0 && r < N) zn[r] = p * di;
}

// ---------------- layer 2 gather: 16 lanes per node ----------------
__global__ void k_gather2(const int* __restrict__ csrc, const int* __restrict__ counts,
                          const float* __restrict__ zn, const float* __restrict__ b2,
                          float* __restrict__ out, int N) {
    int t = blockIdx.x * blockDim.x + threadIdx.x;
    int r = t >> 4, li = t & 15;
    if (r >= N) return;
    size_t beg = (size_t)r * CAP;
    int cnt = counts[r];
    float acc = 0.f;
    for (int j = li; j < cnt; j += 16) {
        acc += zn[csrc[beg + j]];
    }
    acc += __shfl_xor(acc, 1, 64);
    acc += __shfl_xor(acc, 2, 64);
    acc += __shfl_xor(acc, 4, 64);
    acc += __shfl_xor(acc, 8, 64);
    if (li == 0) {
        float di = rsqrtf((float)(cnt + 1));
        out[r] = di * (acc + zn[r]) + b2[0];
    }
}

extern "C" void kernel_launch(void* const* d_in, const int* in_sizes, int n_in,
                              void* d_out, int out_size, void* d_ws, size_t ws_size,
                              hipStream_t stream) {
    const float* x  = (const float*)d_in[0];
    const int*   ei = (const int*)d_in[1];   // [2, E] int32
    const float* W1 = (const float*)d_in[2];
    const float* b1 = (const float*)d_in[3];
    const float* W2 = (const float*)d_in[4];
    const float* b2 = (const float*)d_in[5];
    float* out = (float*)d_out;

    const int N = in_sizes[0] / F_IN;     // 100000
    const int E = in_sizes[1] / 2;        // 1600000
    const int* src = ei;
    const int* dst = ei + E;

    const int nc = (N + CNODES - 1) / CNODES;   // 196 coarse buckets
    const int NBKT = (N + 63) / 64;             // 1563 gemm blocks

    // workspace layout (all 256B-aligned)
    char* ws = (char*)d_ws;
    size_t off = 0;
    auto alloc = [&](size_t bytes) { void* p = ws + off; off += (bytes + 255) & ~255ULL; return p; };
    int*    acur   = (int*)   alloc((size_t)nc * 4);
    int*    counts = (int*)   alloc((size_t)N * 4);
    float*  zn     = (float*) alloc((size_t)N * 4);
    int*    ent    = (int*)   alloc((size_t)nc * BCAPC * 4);  // 7.0 MB
    __half* hn     = (__half*)alloc((size_t)N * HID * 2);     // 12.8 MB
    int*    csrc   = (int*)   alloc((size_t)N * CAP * 4);     // 38.4 MB

    hipMemsetAsync(acur, 0, (size_t)nc * 4, stream);

    const int coarseBlks = (E + CCHUNK - 1) / CCHUNK;   // 391
    k_coarse<<<coarseBlks, 512, 0, stream>>>(src, dst, acur, ent, E, nc);
    k_fillc<<<nc, 1024, 0, stream>>>(acur, ent, counts, csrc, N);
    k_gemm<<<NBKT, 256, 0, stream>>>(x, W1, counts, hn, N);
    k_gather1<<<(N + 7) / 8, 256, 0, stream>>>(csrc, counts, hn, b1, W2, zn, N);
    k_gather2<<<((size_t)N * 16 + 255) / 256, 256, 0, stream>>>(csrc, counts, zn, b2, out, N);
}